// Round 3
// baseline (236.295 us; speedup 1.0000x reference)
//
#include <hip/hip_runtime.h>

// PermuteWeightSharing: out[row, s*16+k] = x[row, ppos[s]*16+k] - x[row, pneg[s]*16+k]
// row = (b,o,i) flattened; 256 floats per row = 16 slots x 16 floats = 64 float4.
// One wave64 <-> one row: lane L holds float4 L of the row (sequential, perfectly
// coalesced load AND store). Slot permutation is done in-register via __shfl
// (ds_bpermute): lane L pulls from lane ppos[L>>2]*4 + (L&3).
//
// Round-3 changes vs round-2 (A/B for the external-floor hypothesis):
//  - single fused kernel: each thread decodes the two argmax indices itself from
//    the 1 KB one-hot matrices (L1-resident after first touch) — no pre-dispatch
//  - 2048 blocks x 256 thr, 16 float4/thread, unrolled x2 -> 2 loads in flight/wave

#define NSLOTS 16

__global__ __launch_bounds__(256) void permute_ws_kernel(
    const float4* __restrict__ x,
    const float* __restrict__ Ppos,
    const float* __restrict__ Pneg,
    float4* __restrict__ out,
    long total_v4)
{
    const int lane = threadIdx.x & 63;
    const int slot = lane >> 2;   // [0,16)
    const int k4   = lane & 3;    // [0,4)

    // decode one-hot rows (1 KB per matrix, L1/L2-resident broadcast reads)
    int ip = 0, in_ = 0;
    #pragma unroll
    for (int j = 0; j < NSLOTS; ++j) {
        if (Ppos[slot * NSLOTS + j] > 0.5f) ip = j;
        if (Pneg[slot * NSLOTS + j] > 0.5f) in_ = j;
    }
    const int src_a = (ip << 2) | k4;
    const int src_b = (in_ << 2) | k4;

    long i = (long)blockIdx.x * blockDim.x + threadIdx.x;
    const long stride = (long)gridDim.x * blockDim.x;   // multiple of 64

    for (; i < total_v4; i += 2 * stride) {
        const long i1 = i + stride;
        const bool has1 = (i1 < total_v4);

        const float4 v0 = x[i];
        const float4 v1 = has1 ? x[i1] : v0;

        float4 r0, r1;
        r0.x = __shfl(v0.x, src_a, 64) - __shfl(v0.x, src_b, 64);
        r0.y = __shfl(v0.y, src_a, 64) - __shfl(v0.y, src_b, 64);
        r0.z = __shfl(v0.z, src_a, 64) - __shfl(v0.z, src_b, 64);
        r0.w = __shfl(v0.w, src_a, 64) - __shfl(v0.w, src_b, 64);
        r1.x = __shfl(v1.x, src_a, 64) - __shfl(v1.x, src_b, 64);
        r1.y = __shfl(v1.y, src_a, 64) - __shfl(v1.y, src_b, 64);
        r1.z = __shfl(v1.z, src_a, 64) - __shfl(v1.z, src_b, 64);
        r1.w = __shfl(v1.w, src_a, 64) - __shfl(v1.w, src_b, 64);

        out[i] = r0;
        if (has1) out[i1] = r1;
    }
}

extern "C" void kernel_launch(void* const* d_in, const int* in_sizes, int n_in,
                              void* d_out, int out_size, void* d_ws, size_t ws_size,
                              hipStream_t stream)
{
    const float4* x    = (const float4*)d_in[0];
    const float*  Ppos = (const float*)d_in[1];
    const float*  Pneg = (const float*)d_in[2];
    float4*       out  = (float4*)d_out;

    const long total_v4 = (long)out_size / 4;   // 8,388,608

    const int block = 256;
    const int grid  = 2048;   // 8192 waves; 16 float4/thread at this size
    permute_ws_kernel<<<grid, block, 0, stream>>>(x, Ppos, Pneg, out, total_v4);
}